// Round 13
// baseline (206.892 us; speedup 1.0000x reference)
//
#include <hip/hip_runtime.h>
#include <cstdint>

#define BB    8
#define CIN   256
#define COUT  256
#define HH    64
#define WW    64

typedef __attribute__((ext_vector_type(8))) short    s16x8;
typedef __attribute__((ext_vector_type(8))) unsigned short u16x8;
typedef __attribute__((ext_vector_type(4))) unsigned short u16x4;
typedef __attribute__((ext_vector_type(4))) float    f32x4;

__device__ __forceinline__ float bf2f(unsigned short u) {
    unsigned int v = ((unsigned int)u) << 16;
    return __builtin_bit_cast(float, v);
}
__device__ __forceinline__ unsigned short f2bf(float f) {   // RNE (pack/epilogue)
    unsigned int u = __builtin_bit_cast(unsigned int, f);
    unsigned int r = (u + 0x7FFFu + ((u >> 16) & 1u)) >> 16;
    return (unsigned short)r;
}
__device__ __forceinline__ unsigned short f2bf_rz(float f) { // truncate (hot blend)
    return (unsigned short)(__builtin_bit_cast(unsigned int, f) >> 16);
}

// ---------------------------------------------------------------------------
// 1) merged packs + stats zeroing, 4640 blocks x 256 thr (unchanged from R12)
__global__ void k_pack(const float* __restrict__ x,
                       const float* __restrict__ w,
                       const float* __restrict__ woff,
                       unsigned short* __restrict__ xT,
                       unsigned short* __restrict__ wTk,
                       unsigned short* __restrict__ wofT,
                       float* __restrict__ gsum,
                       float* __restrict__ gssq) {
    int blk = blockIdx.x;
    int t = threadIdx.x;
    __shared__ float tile[64 * 65];
    if (blk == 0 && t < 256) { gsum[t] = 0.f; gssq[t] = 0.f; }
    if (blk < 2048) {
        int b    = blk & 7;
        int rest = blk >> 3;
        int h    = rest >> 2;
        int c0   = (rest & 3) * 64;
#pragma unroll
        for (int r = 0; r < 16; ++r) {
            int idx = t + r * 256;
            int i = idx >> 6, w_ = idx & 63;
            tile[i * 65 + w_] = x[(((b * 256 + c0 + i) * 64 + h) * 64) + w_];
        }
        __syncthreads();
#pragma unroll
        for (int r = 0; r < 2; ++r) {
            int idx = t + r * 256;          // 0..511 = (w, c8)
            int w_ = idx >> 3;
            int c8 = (idx & 7) * 8;
            u16x8 res;
#pragma unroll
            for (int k = 0; k < 8; ++k) res[k] = f2bf(tile[(c8 + k) * 65 + w_]);
            *reinterpret_cast<u16x8*>(&xT[((b * 64 + h) * 64 + w_) * 256 + c0 + c8]) = res;
        }
    } else if (blk < 4352) {
        int idx = (blk - 2048) * 256 + t;   // 0..589,823
        int j   = idx & 7;
        int q   = (idx >> 3) & 3;
        int o16 = (idx >> 5) & 15;
        int n16 = (idx >> 9) & 15;
        int kc  = (idx >> 13) & 7;
        int tp  = idx >> 16;
        int c = kc * 32 + q * 8 + j;
        int o = n16 * 16 + o16;
        wTk[idx] = f2bf(w[(o * 256 + c) * 9 + tp]);
    } else {
        int idx = (blk - 4352) * 256 + t;   // 0..73,727
        int c  = idx & 255;
        int j  = (idx >> 8) & 31;
        int tp = idx >> 13;
        wofT[idx] = f2bf((j < 27) ? woff[(j * 256 + c) * 9 + tp] : 0.f);
    }
}

// ---------------------------------------------------------------------------
// 2) main kernel, 128-px blocks (2 adjacent rows h0,h1): offconv (B1, each
//    wave owns full K for its 16-px tile) + deform GEMM (B2, producer/consumer,
//    weights loaded once per kc serve BOTH tiles) + epilogue.
// 256 blocks (b = blk&7 XCD affinity, hp = blk>>3), 512 thr = 8 waves.
// LDS (152064 B):
//   [0,135168)       S [tile2][buf2][64*264] u16              | B2
//   [0,71808)        S3 offconv 4-row window (4*66*136 u16)   | B1
//   [0,34816)        T y-tile (256 o x 68 u16)                | epilogue
//   [135168,152064)  OMS om tile (128 px x 33 f32)            | B1 write, B2 read
__global__ __launch_bounds__(512, 2)
void k_main(const unsigned short* __restrict__ xT,
            const unsigned short* __restrict__ wTk,
            const unsigned short* __restrict__ wofT,
            const float* __restrict__ boffg,
            const float* __restrict__ bias,
            unsigned short* __restrict__ y16,
            float* __restrict__ gsum, float* __restrict__ gssq) {
    __shared__ __align__(16) char smem[152064];
    int blk = blockIdx.x;
    int b = blk & 7, hp = blk >> 3;
    int h0 = hp * 2;
    int pblk0 = b * 64 + h0;
    int t = threadIdx.x;
    int lane = t & 63, wv = t >> 6;
    int lm = lane & 15, q = lane >> 4;
    const f32x4 FZ = {0.f, 0.f, 0.f, 0.f};
    float* OMS = (float*)(smem + 135168);            // [128][33]

    // ====== Phase B1: offset conv -> OMS (8 waves x 16-px tiles, full K) =====
    {
        unsigned short* S3 = (unsigned short*)smem;  // [4][66][136]
        f32x4 oacc0 = FZ, oacc1 = FZ;
        int p0w   = (wv & 3) * 16;                   // px within h-tile
        int hbase = wv >> 2;                         // 0: h0-tile, 1: h1-tile
        for (int cc = 0; cc < 2; ++cc) {
            __syncthreads();
            if (t < 128) {   // zero w=0 / w=65 pad columns (4 rows)
                int rr = t >> 5, col = (t >> 4) & 1, c8 = (t & 15) * 8;
                u16x8 z = {0,0,0,0,0,0,0,0};
                *reinterpret_cast<u16x8*>(&S3[(rr * 66 + col * 65) * 136 + c8]) = z;
            }
#pragma unroll
            for (int r = 0; r < 8; ++r) {
                int v = t + r * 512;                 // 4 rows x 64 w x 16 chunks
                int rr = v >> 10, rem = v & 1023;
                int w_ = rem >> 4, c8 = (rem & 15) * 8;
                int hr = h0 - 1 + rr;
                u16x8 d = {0,0,0,0,0,0,0,0};
                if (hr >= 0 && hr < 64)
                    d = *reinterpret_cast<const u16x8*>(xT + ((b * 64 + hr) * 64 + w_) * 256 + cc * 128 + c8);
                *reinterpret_cast<u16x8*>(&S3[(rr * 66 + w_ + 1) * 136 + c8]) = d;
            }
            __syncthreads();
            {
                int boff = cc * 128 + q * 8;
                s16x8 pb[8], nb[8];
                {
                    const unsigned short* wb = wofT + lm * 256 + boff;
#pragma unroll
                    for (int kc = 0; kc < 4; ++kc) {
                        pb[kc]     = *reinterpret_cast<const s16x8*>(wb + kc * 32);
                        pb[4 + kc] = *reinterpret_cast<const s16x8*>(wb + 4096 + kc * 32);
                    }
                }
#pragma unroll
                for (int tp = 0; tp < 9; ++tp) {
                    if (tp < 8) {
                        const unsigned short* wb = wofT + ((tp + 1) * 32 + lm) * 256 + boff;
#pragma unroll
                        for (int kc = 0; kc < 4; ++kc) {
                            nb[kc]     = *reinterpret_cast<const s16x8*>(wb + kc * 32);
                            nb[4 + kc] = *reinterpret_cast<const s16x8*>(wb + 4096 + kc * 32);
                        }
                    }
                    int dh = tp / 3, dw_ = tp % 3;
                    int arow = ((dh + hbase) * 66 + p0w + lm + dw_) * 136 + q * 8;
#pragma unroll
                    for (int kc = 0; kc < 4; ++kc) {
                        s16x8 a = *reinterpret_cast<const s16x8*>(&S3[arow + kc * 32]);
                        oacc0 = __builtin_amdgcn_mfma_f32_16x16x32_bf16(a, pb[kc],     oacc0, 0, 0, 0);
                        oacc1 = __builtin_amdgcn_mfma_f32_16x16x32_bf16(a, pb[4 + kc], oacc1, 0, 0, 0);
                    }
#pragma unroll
                    for (int i = 0; i < 8; ++i) pb[i] = nb[i];
                }
            }
        }
        __syncthreads();
#pragma unroll
        for (int n = 0; n < 2; ++n) {
            int j = n * 16 + lm;
            float bj = (j < 27) ? boffg[j] : 0.f;
            f32x4 a = n ? oacc1 : oacc0;
#pragma unroll
            for (int i = 0; i < 4; ++i) {
                int pg = hbase * 64 + p0w + q * 4 + i;
                OMS[pg * 33 + j] = a[i] + bj;
            }
        }
        __syncthreads();   // OMS ready; S3 reads done before S writes
    }

    // ================= Phase B2: main GEMM (producer/consumer) ==============
    unsigned short* S = (unsigned short*)smem;       // [(tile<<1)|buf][64*264]
    f32x4 acc[8][4];                                 // [tile*4+mt][n]
#pragma unroll
    for (int m = 0; m < 8; ++m)
#pragma unroll
        for (int n = 0; n < 4; ++n) acc[m][n] = FZ;

    if (wv >= 4) {
        // ------------------------- producer -------------------------
        int pw = wv - 4;
        int s  = lane & 7;                 // 16B sub-chunk within 128B window
        int pA = pw * 16 + (lane >> 3);    // local px group A (8 lanes each)
        int pB = pA + 8;                   // local px group B
        int rb = b * 4096;

        float wgA[4], wgB[4], wgC[4], wgD[4];
        int   adA[4], adB[4], adC[4], adD[4];

        auto setup = [&](int tp, int tile, int p, float* wgt, int* ad) {
            int pg = tile * 64 + p;
            float oh = OMS[pg * 33 + 2 * tp];
            float ow = OMS[pg * 33 + 2 * tp + 1];
            float mv = OMS[pg * 33 + 18 + tp];
            float mk = 1.f / (1.f + __expf(-mv));
            float ph = (float)(h0 + tile + tp / 3 - 1) + oh;
            float pw_ = (float)(p + tp % 3 - 1) + ow;
            float fh0 = floorf(ph), fw0 = floorf(pw_);
            int ih0 = (int)fh0, iw0 = (int)fw0;
            float lh = ph - fh0, lw = pw_ - fw0;
            float hh = 1.f - lh, hw_ = 1.f - lw;
            bool vh0 = (ih0 >= 0) & (ih0 < 64);
            bool vh1 = (ih0 + 1 >= 0) & (ih0 + 1 < 64);
            bool vw0 = (iw0 >= 0) & (iw0 < 64);
            bool vw1 = (iw0 + 1 >= 0) & (iw0 + 1 < 64);
            wgt[0] = hh * hw_ * mk * (float)(vh0 & vw0);
            wgt[1] = hh * lw  * mk * (float)(vh0 & vw1);
            wgt[2] = lh * hw_ * mk * (float)(vh1 & vw0);
            wgt[3] = lh * lw  * mk * (float)(vh1 & vw1);
            int ch0 = min(max(ih0, 0), 63), ch1 = min(max(ih0 + 1, 0), 63);
            int cw0 = min(max(iw0, 0), 63), cw1 = min(max(iw0 + 1, 0), 63);
            ad[0] = ((rb + ch0 * 64 + cw0) * 256);
            ad[1] = ((rb + ch0 * 64 + cw1) * 256);
            ad[2] = ((rb + ch1 * 64 + cw0) * 256);
            ad[3] = ((rb + ch1 * 64 + cw1) * 256);
        };

        u16x8 rP[4], rQ[4];
        auto issueSet = [&](const int* ad, int j, u16x8* r) {
            int off = j * 64 + s * 8;
#pragma unroll
            for (int c = 0; c < 4; ++c)
                r[c] = *reinterpret_cast<const u16x8*>(xT + ad[c] + off);
        };
        auto blendSet = [&](int tile, int buf, int p, const float* wgt, int j, u16x8* r) {
            u16x8 res;
#pragma unroll
            for (int k = 0; k < 8; ++k) {
                float v = wgt[0] * bf2f(r[0][k]);
                v = fmaf(wgt[1], bf2f(r[1][k]), v);
                v = fmaf(wgt[2], bf2f(r[2][k]), v);
                v = fmaf(wgt[3], bf2f(r[3][k]), v);
                res[k] = f2bf_rz(v);
            }
            *reinterpret_cast<u16x8*>(
                &S[((tile << 1) | buf) * 16896 + p * 264 + j * 64 + s * 8]) = res;
        };
        auto fillTap = [&](int tp, int buf) {
            setup(tp, 0, pA, wgA, adA);
            setup(tp, 0, pB, wgB, adB);
            setup(tp, 1, pA, wgC, adC);
            setup(tp, 1, pB, wgD, adD);
            issueSet(adA, 0, rP);              issueSet(adA, 1, rQ);
            blendSet(0, buf, pA, wgA, 0, rP);  issueSet(adA, 2, rP);
            blendSet(0, buf, pA, wgA, 1, rQ);  issueSet(adA, 3, rQ);
            blendSet(0, buf, pA, wgA, 2, rP);  issueSet(adB, 0, rP);
            blendSet(0, buf, pA, wgA, 3, rQ);  issueSet(adB, 1, rQ);
            blendSet(0, buf, pB, wgB, 0, rP);  issueSet(adB, 2, rP);
            blendSet(0, buf, pB, wgB, 1, rQ);  issueSet(adB, 3, rQ);
            blendSet(0, buf, pB, wgB, 2, rP);  issueSet(adC, 0, rP);
            blendSet(0, buf, pB, wgB, 3, rQ);  issueSet(adC, 1, rQ);
            blendSet(1, buf, pA, wgC, 0, rP);  issueSet(adC, 2, rP);
            blendSet(1, buf, pA, wgC, 1, rQ);  issueSet(adC, 3, rQ);
            blendSet(1, buf, pA, wgC, 2, rP);  issueSet(adD, 0, rP);
            blendSet(1, buf, pA, wgC, 3, rQ);  issueSet(adD, 1, rQ);
            blendSet(1, buf, pB, wgD, 0, rP);  issueSet(adD, 2, rP);
            blendSet(1, buf, pB, wgD, 1, rQ);  issueSet(adD, 3, rQ);
            blendSet(1, buf, pB, wgD, 2, rP);
            blendSet(1, buf, pB, wgD, 3, rQ);
        };

        fillTap(0, 0);
        __syncthreads();
        for (int tp = 0; tp < 9; ++tp) {
            if (tp < 8) fillTap(tp + 1, (tp + 1) & 1);
            __syncthreads();
        }
    } else {
        // ------------------------- consumer -------------------------
        __syncthreads();               // matches producer prologue barrier
        for (int tp = 0; tp < 9; ++tp) {
            int cur = tp & 1;
            const unsigned short* Sc0 = &S[cur * 16896];
            const unsigned short* Sc1 = &S[(2 | cur) * 16896];
            const unsigned short* wtap = wTk + (size_t)tp * 65536
                                       + (size_t)(wv * 4) * 512 + lm * 32 + q * 8;
            s16x8 wbuf[2][4];
#pragma unroll
            for (int n = 0; n < 4; ++n)
                wbuf[0][n] = *reinterpret_cast<const s16x8*>(wtap + n * 512);
#pragma unroll
            for (int kc = 0; kc < 8; ++kc) {
                if (kc < 7) {
                    const unsigned short* wb = wtap + (kc + 1) * 8192;
#pragma unroll
                    for (int n = 0; n < 4; ++n)
                        wbuf[(kc + 1) & 1][n] = *reinterpret_cast<const s16x8*>(wb + n * 512);
                }
#pragma unroll
                for (int mt = 0; mt < 4; ++mt) {
                    s16x8 a0 = *reinterpret_cast<const s16x8*>(
                        &Sc0[(mt * 16 + lm) * 264 + kc * 32 + q * 8]);
                    s16x8 a1 = *reinterpret_cast<const s16x8*>(
                        &Sc1[(mt * 16 + lm) * 264 + kc * 32 + q * 8]);
#pragma unroll
                    for (int n = 0; n < 4; ++n) {
                        acc[mt][n]     = __builtin_amdgcn_mfma_f32_16x16x32_bf16(
                            a0, wbuf[kc & 1][n], acc[mt][n], 0, 0, 0);
                        acc[4 + mt][n] = __builtin_amdgcn_mfma_f32_16x16x32_bf16(
                            a1, wbuf[kc & 1][n], acc[4 + mt][n], 0, 0, 0);
                    }
                }
            }
            __syncthreads();
        }
    }

    // ====== epilogue: per tile, LDS untile (T o-major) + coalesced y16 ======
    unsigned short* T = (unsigned short*)smem;       // [256 o][68]
    float sacc[4] = {0.f, 0.f, 0.f, 0.f};
    float ssacc[4] = {0.f, 0.f, 0.f, 0.f};
    for (int tile = 0; tile < 2; ++tile) {
        __syncthreads();               // S reads / prev T stores complete
        if (wv < 4) {
#pragma unroll
            for (int nt = 0; nt < 4; ++nt) {
                int o = wv * 64 + nt * 16 + lm;
                float bo = bias[o];
#pragma unroll
                for (int mt = 0; mt < 4; ++mt) {
#pragma unroll
                    for (int i = 0; i < 4; ++i) {
                        float v = acc[tile * 4 + mt][nt][i] + bo;
                        T[o * 68 + mt * 16 + q * 4 + i] = f2bf(v);
                        sacc[nt] += v; ssacc[nt] += v * v;
                    }
                }
            }
        }
        __syncthreads();
        u16x4* yv = reinterpret_cast<u16x4*>(y16) + (size_t)(pblk0 + tile) * 4096;
#pragma unroll
        for (int k = 0; k < 8; ++k) {
            int u = t + k * 512;       // 0..4095: o = u>>4, g2 = u&15
            int o = u >> 4, g2 = u & 15;
            yv[o * 16 + g2] = *reinterpret_cast<const u16x4*>(&T[o * 68 + g2 * 4]);
        }
    }
    if (wv < 4) {
#pragma unroll
        for (int nt = 0; nt < 4; ++nt) {
            int o = wv * 64 + nt * 16 + lm;
            float sa = sacc[nt], ss = ssacc[nt];
            sa += __shfl_xor(sa, 16);
            sa += __shfl_xor(sa, 32);
            ss += __shfl_xor(ss, 16);
            ss += __shfl_xor(ss, 32);
            if (q == 0) {
                atomicAdd(&gsum[o], sa);
                atomicAdd(&gssq[o], ss);
            }
        }
    }
}

// ---------------------------------------------------------------------------
// 3) BN + ReLU: pure elementwise (y16 is [pblk][o][px]); unchanged from R12.
__global__ void k_bnrelu(const unsigned short* __restrict__ y16,
                         const float* __restrict__ gsum, const float* __restrict__ gssq,
                         const float* __restrict__ gamma, const float* __restrict__ beta,
                         float* __restrict__ out) {
    int i = blockIdx.x;
    int t = threadIdx.x;
    int b    = i & 7;
    int rest = i >> 3;                 // 0..255
    int h    = rest & 63;
    int o0   = (rest >> 6) * 64;
    int pblk = b * 64 + h;
    __shared__ float sc[64], sh[64];
    if (t < 64) {
        int o = o0 + t;
        const float invn = 1.f / 32768.f;
        float mean = gsum[o] * invn;
        float var = gssq[o] * invn - mean * mean;
        float inv = rsqrtf(var + 1e-5f);
        float s = gamma[o] * inv;
        sc[t] = s;
        sh[t] = beta[o] - mean * s;
    }
    __syncthreads();
    const u16x8* yv = reinterpret_cast<const u16x8*>(
        y16 + ((size_t)pblk * 256 + o0) * 64);
    float* obase = out + ((size_t)b * 256 + o0) * 4096 + h * 64;
#pragma unroll
    for (int r = 0; r < 2; ++r) {
        int c = t + r * 256;           // 0..511: row = c>>3 (o-local), g = c&7
        int row = c >> 3, g = c & 7;
        u16x8 d = yv[row * 8 + g];
        float scl = sc[row], shf = sh[row];
        float4 v0, v1;
        v0.x = fmaxf(bf2f(d[0]) * scl + shf, 0.f);
        v0.y = fmaxf(bf2f(d[1]) * scl + shf, 0.f);
        v0.z = fmaxf(bf2f(d[2]) * scl + shf, 0.f);
        v0.w = fmaxf(bf2f(d[3]) * scl + shf, 0.f);
        v1.x = fmaxf(bf2f(d[4]) * scl + shf, 0.f);
        v1.y = fmaxf(bf2f(d[5]) * scl + shf, 0.f);
        v1.z = fmaxf(bf2f(d[6]) * scl + shf, 0.f);
        v1.w = fmaxf(bf2f(d[7]) * scl + shf, 0.f);
        float* op = obase + row * 4096 + g * 8;
        *reinterpret_cast<float4*>(op)     = v0;
        *reinterpret_cast<float4*>(op + 4) = v1;
    }
}

// ---------------------------------------------------------------------------
extern "C" void kernel_launch(void* const* d_in, const int* in_sizes, int n_in,
                              void* d_out, int out_size, void* d_ws, size_t ws_size,
                              hipStream_t stream) {
    const float* x      = (const float*)d_in[0];
    const float* w_off  = (const float*)d_in[1];
    const float* b_off  = (const float*)d_in[2];
    const float* weight = (const float*)d_in[3];
    const float* bias   = (const float*)d_in[4];
    const float* gamma  = (const float*)d_in[5];
    const float* beta   = (const float*)d_in[6];

    char* ws = (char*)d_ws;
    const size_t OFF_XT    = 0;                       // 16,777,216  bf16 xT
    const size_t OFF_WT    = OFF_XT + 16777216;       //  1,179,648  bf16 wTk
    const size_t OFF_WOFT  = OFF_WT + 1179648;        //    147,456  bf16 wofT
    const size_t OFF_Y16   = OFF_WOFT + 147456;       // 16,777,216  bf16 y [pblk][o][px]
    const size_t OFF_SUM   = OFF_Y16 + 16777216;      //      1,024
    const size_t OFF_SUMSQ = OFF_SUM + 1024;          //      1,024

    unsigned short* xT   = (unsigned short*)(ws + OFF_XT);
    unsigned short* wTk  = (unsigned short*)(ws + OFF_WT);
    unsigned short* wofT = (unsigned short*)(ws + OFF_WOFT);
    unsigned short* y16  = (unsigned short*)(ws + OFF_Y16);
    float* gsum  = (float*)(ws + OFF_SUM);
    float* gssq  = (float*)(ws + OFF_SUMSQ);

    k_pack  <<<4640, 256, 0, stream>>>(x, weight, w_off, xT, wTk, wofT, gsum, gssq);
    k_main  <<< 256, 512, 0, stream>>>(xT, wTk, wofT, b_off, bias, y16, gsum, gssq);
    k_bnrelu<<<2048, 256, 0, stream>>>(y16, gsum, gssq, gamma, beta, (float*)d_out);
}

// Round 14
// 202.117 us; speedup vs baseline: 1.0236x; 1.0236x over previous
//
#include <hip/hip_runtime.h>
#include <cstdint>

#define BB    8
#define CIN   256
#define COUT  256
#define HH    64
#define WW    64

typedef __attribute__((ext_vector_type(8))) short    s16x8;
typedef __attribute__((ext_vector_type(8))) unsigned short u16x8;
typedef __attribute__((ext_vector_type(4))) unsigned short u16x4;
typedef __attribute__((ext_vector_type(4))) float    f32x4;

__device__ __forceinline__ float bf2f(unsigned short u) {
    unsigned int v = ((unsigned int)u) << 16;
    return __builtin_bit_cast(float, v);
}
__device__ __forceinline__ unsigned short f2bf(float f) {   // RNE (pack/epilogue)
    unsigned int u = __builtin_bit_cast(unsigned int, f);
    unsigned int r = (u + 0x7FFFu + ((u >> 16) & 1u)) >> 16;
    return (unsigned short)r;
}
__device__ __forceinline__ unsigned short f2bf_rz(float f) { // truncate (hot blend)
    return (unsigned short)(__builtin_bit_cast(unsigned int, f) >> 16);
}

// ---------------------------------------------------------------------------
// 1) merged packs + stats zeroing, 4640 blocks x 256 thr (unchanged from R12)
__global__ void k_pack(const float* __restrict__ x,
                       const float* __restrict__ w,
                       const float* __restrict__ woff,
                       unsigned short* __restrict__ xT,
                       unsigned short* __restrict__ wTk,
                       unsigned short* __restrict__ wofT,
                       float* __restrict__ gsum,
                       float* __restrict__ gssq) {
    int blk = blockIdx.x;
    int t = threadIdx.x;
    __shared__ float tile[64 * 65];
    if (blk == 0 && t < 256) { gsum[t] = 0.f; gssq[t] = 0.f; }
    if (blk < 2048) {
        int b    = blk & 7;
        int rest = blk >> 3;
        int h    = rest >> 2;
        int c0   = (rest & 3) * 64;
#pragma unroll
        for (int r = 0; r < 16; ++r) {
            int idx = t + r * 256;
            int i = idx >> 6, w_ = idx & 63;
            tile[i * 65 + w_] = x[(((b * 256 + c0 + i) * 64 + h) * 64) + w_];
        }
        __syncthreads();
#pragma unroll
        for (int r = 0; r < 2; ++r) {
            int idx = t + r * 256;          // 0..511 = (w, c8)
            int w_ = idx >> 3;
            int c8 = (idx & 7) * 8;
            u16x8 res;
#pragma unroll
            for (int k = 0; k < 8; ++k) res[k] = f2bf(tile[(c8 + k) * 65 + w_]);
            *reinterpret_cast<u16x8*>(&xT[((b * 64 + h) * 64 + w_) * 256 + c0 + c8]) = res;
        }
    } else if (blk < 4352) {
        int idx = (blk - 2048) * 256 + t;   // 0..589,823
        int j   = idx & 7;
        int q   = (idx >> 3) & 3;
        int o16 = (idx >> 5) & 15;
        int n16 = (idx >> 9) & 15;
        int kc  = (idx >> 13) & 7;
        int tp  = idx >> 16;
        int c = kc * 32 + q * 8 + j;
        int o = n16 * 16 + o16;
        wTk[idx] = f2bf(w[(o * 256 + c) * 9 + tp]);
    } else {
        int idx = (blk - 4352) * 256 + t;   // 0..73,727
        int c  = idx & 255;
        int j  = (idx >> 8) & 31;
        int tp = idx >> 13;
        wofT[idx] = f2bf((j < 27) ? woff[(j * 256 + c) * 9 + tp] : 0.f);
    }
}

// ---------------------------------------------------------------------------
// 2) main kernel (R12 structure): offconv (B1) + deform GEMM (B2,
//    producer/consumer with 4-DEEP producer gather pipeline) + epilogue.
// 512 blocks (one per (b,h), b=blk&7 XCD affinity), 512 thr = 8 waves.
// LDS union (76032 B):
//   [0,53856)     S3 offconv 3-row window (3*66*136 u16)     | B1
//   [53856,62304) PART offconv partial sums (64x33 f32)      | B1
//   [0,67584)     S sampled-tap double buffer (2x64x264 u16) | B2
//   [0,34816)     T y-tile (256 o x 68 u16)                  | epilogue
//   [67584,76032) OMS om tile (64x33 f32)                    | B1 write, B2 read
__global__ __launch_bounds__(512, 4)
void k_main(const unsigned short* __restrict__ xT,
            const unsigned short* __restrict__ wTk,
            const unsigned short* __restrict__ wofT,
            const float* __restrict__ boffg,
            const float* __restrict__ bias,
            unsigned short* __restrict__ y16,
            float* __restrict__ gsum, float* __restrict__ gssq) {
    __shared__ __align__(16) char smem[76032];
    int blk = blockIdx.x;
    int b = blk & 7, h = blk >> 3;
    int pblk = b * 64 + h;
    int t = threadIdx.x;
    int lane = t & 63, wv = t >> 6;
    int lm = lane & 15, q = lane >> 4;
    const f32x4 FZ = {0.f, 0.f, 0.f, 0.f};

    // ===== Phase B1: offset conv -> OMS (8-wave kc-split, B prefetch) =====
    {
        unsigned short* S3 = (unsigned short*)smem;          // [3*66*136]
        float* PART = (float*)(smem + 53856);                // [64*33]
        float* OMS  = (float*)(smem + 67584);                // [64*33]
        f32x4 oacc0 = FZ, oacc1 = FZ;
        int myTile = wv & 3;            // px tile (16 px)
        int myKH   = wv >> 2;           // kc half
        int p0w = myTile * 16;
        for (int cc = 0; cc < 2; ++cc) {
            __syncthreads();
            if (t < 96) {    // zero w=0 / w=65 pad columns
                int rr = t >> 5, col = (t >> 4) & 1, c8 = (t & 15) * 8;
                u16x8 z = {0,0,0,0,0,0,0,0};
                *reinterpret_cast<u16x8*>(&S3[(rr * 66 + col * 65) * 136 + c8]) = z;
            }
#pragma unroll
            for (int r = 0; r < 6; ++r) {
                int v = t + r * 512;               // over 3*64*16 vec8 units
                int rr = v >> 10, rem = v & 1023;
                int w_ = rem >> 4, c8 = (rem & 15) * 8;
                int hr = h + rr - 1;
                u16x8 d = {0,0,0,0,0,0,0,0};
                if (hr >= 0 && hr < 64)
                    d = *reinterpret_cast<const u16x8*>(xT + ((b * 64 + hr) * 64 + w_) * 256 + cc * 128 + c8);
                *reinterpret_cast<u16x8*>(&S3[(rr * 66 + w_ + 1) * 136 + c8]) = d;
            }
            __syncthreads();
            {
                int boff = cc * 128 + myKH * 64 + q * 8;
                s16x8 pb[4], nb[4];
                {
                    const unsigned short* wb = wofT + (0 * 32 + lm) * 256 + boff;
                    pb[0] = *reinterpret_cast<const s16x8*>(wb);
                    pb[1] = *reinterpret_cast<const s16x8*>(wb + 32);
                    pb[2] = *reinterpret_cast<const s16x8*>(wb + 16 * 256);
                    pb[3] = *reinterpret_cast<const s16x8*>(wb + 16 * 256 + 32);
                }
#pragma unroll
                for (int tp = 0; tp < 9; ++tp) {
                    if (tp < 8) {
                        const unsigned short* wb = wofT + ((tp + 1) * 32 + lm) * 256 + boff;
                        nb[0] = *reinterpret_cast<const s16x8*>(wb);
                        nb[1] = *reinterpret_cast<const s16x8*>(wb + 32);
                        nb[2] = *reinterpret_cast<const s16x8*>(wb + 16 * 256);
                        nb[3] = *reinterpret_cast<const s16x8*>(wb + 16 * 256 + 32);
                    }
                    int dh = tp / 3, dw_ = tp % 3;
                    int arow = (dh * 66 + p0w + lm + dw_) * 136 + myKH * 64 + q * 8;
                    s16x8 a0 = *reinterpret_cast<const s16x8*>(&S3[arow]);
                    s16x8 a1 = *reinterpret_cast<const s16x8*>(&S3[arow + 32]);
                    oacc0 = __builtin_amdgcn_mfma_f32_16x16x32_bf16(a0, pb[0], oacc0, 0, 0, 0);
                    oacc0 = __builtin_amdgcn_mfma_f32_16x16x32_bf16(a1, pb[1], oacc0, 0, 0, 0);
                    oacc1 = __builtin_amdgcn_mfma_f32_16x16x32_bf16(a0, pb[2], oacc1, 0, 0, 0);
                    oacc1 = __builtin_amdgcn_mfma_f32_16x16x32_bf16(a1, pb[3], oacc1, 0, 0, 0);
#pragma unroll
                    for (int i = 0; i < 4; ++i) pb[i] = nb[i];
                }
            }
        }
        __syncthreads();
        if (wv >= 4) {                  // upper kc-half writes partials
#pragma unroll
            for (int i = 0; i < 4; ++i) {
                int prow = p0w + q * 4 + i;
                PART[prow * 33 + lm]      = oacc0[i];
                PART[prow * 33 + 16 + lm] = oacc1[i];
            }
        }
        __syncthreads();
        if (wv < 4) {                   // lower half combines + bias -> OMS
#pragma unroll
            for (int n = 0; n < 2; ++n) {
                int j = n * 16 + lm;
                float bj = (j < 27) ? boffg[j] : 0.f;
                f32x4 a = n ? oacc1 : oacc0;
#pragma unroll
                for (int i = 0; i < 4; ++i) {
                    int prow = p0w + q * 4 + i;
                    OMS[prow * 33 + j] = a[i] + PART[prow * 33 + j] + bj;
                }
            }
        }
        __syncthreads();   // OMS ready; S3/PART reads done before S writes
    }

    // ================= Phase B2: main GEMM (producer/consumer) ==============
    unsigned short* S = (unsigned short*)smem;               // [2][64*264]
    float* OMS = (float*)(smem + 67584);
    f32x4 acc[4][4];
#pragma unroll
    for (int m = 0; m < 4; ++m)
#pragma unroll
        for (int n = 0; n < 4; ++n) acc[m][n] = FZ;

    if (wv >= 4) {
        // --------------- producer (4-deep gather pipeline) ---------------
        int pw = wv - 4;
        int s  = lane & 7;                 // 16B sub-chunk within 128B window
        int pA = pw * 16 + (lane >> 3);    // group A pixel (8 lanes each)
        int pB = pA + 8;                   // group B pixel
        int rb = b * 4096;

        float wgA[4], wgB[4];
        int   adA[4], adB[4];

        auto setup = [&](int tp, int p, float* wgt, int* ad) {
            float oh = OMS[p * 33 + 2 * tp];
            float ow = OMS[p * 33 + 2 * tp + 1];
            float mv = OMS[p * 33 + 18 + tp];
            float mk = 1.f / (1.f + __expf(-mv));
            float ph = (float)(h + tp / 3 - 1) + oh;
            float pw_ = (float)(p + tp % 3 - 1) + ow;
            float fh0 = floorf(ph), fw0 = floorf(pw_);
            int ih0 = (int)fh0, iw0 = (int)fw0;
            float lh = ph - fh0, lw = pw_ - fw0;
            float hh = 1.f - lh, hw_ = 1.f - lw;
            bool vh0 = (ih0 >= 0) & (ih0 < 64);
            bool vh1 = (ih0 + 1 >= 0) & (ih0 + 1 < 64);
            bool vw0 = (iw0 >= 0) & (iw0 < 64);
            bool vw1 = (iw0 + 1 >= 0) & (iw0 + 1 < 64);
            wgt[0] = hh * hw_ * mk * (float)(vh0 & vw0);
            wgt[1] = hh * lw  * mk * (float)(vh0 & vw1);
            wgt[2] = lh * hw_ * mk * (float)(vh1 & vw0);
            wgt[3] = lh * lw  * mk * (float)(vh1 & vw1);
            int ch0 = min(max(ih0, 0), 63), ch1 = min(max(ih0 + 1, 0), 63);
            int cw0 = min(max(iw0, 0), 63), cw1 = min(max(iw0 + 1, 0), 63);
            ad[0] = ((rb + ch0 * 64 + cw0) * 256);
            ad[1] = ((rb + ch0 * 64 + cw1) * 256);
            ad[2] = ((rb + ch1 * 64 + cw0) * 256);
            ad[3] = ((rb + ch1 * 64 + cw1) * 256);
        };

        u16x8 rP[4], rQ[4], rR[4], rS[4];
        auto issueSet = [&](const int* ad, int j, u16x8* r) {
            int off = j * 64 + s * 8;
#pragma unroll
            for (int c = 0; c < 4; ++c)
                r[c] = *reinterpret_cast<const u16x8*>(xT + ad[c] + off);
        };
        auto blendSet = [&](int buf, int p, const float* wgt, int j, u16x8* r) {
            u16x8 res;
#pragma unroll
            for (int k = 0; k < 8; ++k) {
                float v = wgt[0] * bf2f(r[0][k]);
                v = fmaf(wgt[1], bf2f(r[1][k]), v);
                v = fmaf(wgt[2], bf2f(r[2][k]), v);
                v = fmaf(wgt[3], bf2f(r[3][k]), v);
                res[k] = f2bf_rz(v);
            }
            *reinterpret_cast<u16x8*>(&S[buf * 16896 + p * 264 + j * 64 + s * 8]) = res;
        };
        // 4 sets in flight: blend(i) waits for a load issued 4 blends earlier.
        auto fillTap = [&](int tp, int buf) {
            setup(tp, pA, wgA, adA);
            setup(tp, pB, wgB, adB);
            issueSet(adA, 0, rP);
            issueSet(adA, 1, rQ);
            issueSet(adA, 2, rR);
            issueSet(adA, 3, rS);
            blendSet(buf, pA, wgA, 0, rP);  issueSet(adB, 0, rP);
            blendSet(buf, pA, wgA, 1, rQ);  issueSet(adB, 1, rQ);
            blendSet(buf, pA, wgA, 2, rR);  issueSet(adB, 2, rR);
            blendSet(buf, pA, wgA, 3, rS);  issueSet(adB, 3, rS);
            blendSet(buf, pB, wgB, 0, rP);
            blendSet(buf, pB, wgB, 1, rQ);
            blendSet(buf, pB, wgB, 2, rR);
            blendSet(buf, pB, wgB, 3, rS);
        };

        fillTap(0, 0);
        __syncthreads();
        for (int tp = 0; tp < 9; ++tp) {
            if (tp < 8) fillTap(tp + 1, (tp + 1) & 1);
            __syncthreads();
        }
    } else {
        // ------------------------- consumer -------------------------
        __syncthreads();               // matches producer prologue barrier
        for (int tp = 0; tp < 9; ++tp) {
            const unsigned short* Sc = &S[(tp & 1) * 16896];
            const unsigned short* wtap = wTk + (size_t)tp * 65536
                                       + (size_t)(wv * 4) * 512 + lm * 32 + q * 8;
            s16x8 wbuf[2][4];
#pragma unroll
            for (int n = 0; n < 4; ++n)
                wbuf[0][n] = *reinterpret_cast<const s16x8*>(wtap + n * 512);
#pragma unroll
            for (int kc = 0; kc < 8; ++kc) {
                if (kc < 7) {
                    const unsigned short* wb = wtap + (kc + 1) * 8192;
#pragma unroll
                    for (int n = 0; n < 4; ++n)
                        wbuf[(kc + 1) & 1][n] = *reinterpret_cast<const s16x8*>(wb + n * 512);
                }
#pragma unroll
                for (int mt = 0; mt < 4; ++mt) {
                    s16x8 a = *reinterpret_cast<const s16x8*>(
                        &Sc[(mt * 16 + lm) * 264 + kc * 32 + q * 8]);
#pragma unroll
                    for (int n = 0; n < 4; ++n)
                        acc[mt][n] = __builtin_amdgcn_mfma_f32_16x16x32_bf16(
                            a, wbuf[kc & 1][n], acc[mt][n], 0, 0, 0);
                }
            }
            __syncthreads();
        }
    }

    // ====== epilogue: LDS untile (T o-major) + stats + coalesced y16 ======
    unsigned short* T = (unsigned short*)smem;    // [256 o][68]
    if (wv < 4) {
#pragma unroll
        for (int nt = 0; nt < 4; ++nt) {
            int o = wv * 64 + nt * 16 + lm;
            float bo = bias[o];
            float sacc = 0.f, ssacc = 0.f;
#pragma unroll
            for (int mt = 0; mt < 4; ++mt) {
#pragma unroll
                for (int i = 0; i < 4; ++i) {
                    float v = acc[mt][nt][i] + bo;
                    T[o * 68 + mt * 16 + q * 4 + i] = f2bf(v);
                    sacc += v; ssacc += v * v;
                }
            }
            sacc  += __shfl_xor(sacc, 16);
            sacc  += __shfl_xor(sacc, 32);
            ssacc += __shfl_xor(ssacc, 16);
            ssacc += __shfl_xor(ssacc, 32);
            if (q == 0) {
                atomicAdd(&gsum[o], sacc);
                atomicAdd(&gssq[o], ssacc);
            }
        }
    }
    __syncthreads();
    // cooperative store: y16[pblk][o][px] contiguous (512B/inst per wave)
    u16x4* yv = reinterpret_cast<u16x4*>(y16) + (size_t)pblk * 4096;
#pragma unroll
    for (int k = 0; k < 8; ++k) {
        int u = t + k * 512;           // 0..4095: o = u>>4, g2 = u&15
        int o = u >> 4, g2 = u & 15;
        yv[o * 16 + g2] = *reinterpret_cast<const u16x4*>(&T[o * 68 + g2 * 4]);
    }
}

// ---------------------------------------------------------------------------
// 3) BN + ReLU: pure elementwise (y16 is [pblk][o][px]); unchanged from R12.
__global__ void k_bnrelu(const unsigned short* __restrict__ y16,
                         const float* __restrict__ gsum, const float* __restrict__ gssq,
                         const float* __restrict__ gamma, const float* __restrict__ beta,
                         float* __restrict__ out) {
    int i = blockIdx.x;
    int t = threadIdx.x;
    int b    = i & 7;
    int rest = i >> 3;                 // 0..255
    int h    = rest & 63;
    int o0   = (rest >> 6) * 64;
    int pblk = b * 64 + h;
    __shared__ float sc[64], sh[64];
    if (t < 64) {
        int o = o0 + t;
        const float invn = 1.f / 32768.f;
        float mean = gsum[o] * invn;
        float var = gssq[o] * invn - mean * mean;
        float inv = rsqrtf(var + 1e-5f);
        float s = gamma[o] * inv;
        sc[t] = s;
        sh[t] = beta[o] - mean * s;
    }
    __syncthreads();
    const u16x8* yv = reinterpret_cast<const u16x8*>(
        y16 + ((size_t)pblk * 256 + o0) * 64);
    float* obase = out + ((size_t)b * 256 + o0) * 4096 + h * 64;
#pragma unroll
    for (int r = 0; r < 2; ++r) {
        int c = t + r * 256;           // 0..511: row = c>>3 (o-local), g = c&7
        int row = c >> 3, g = c & 7;
        u16x8 d = yv[row * 8 + g];
        float scl = sc[row], shf = sh[row];
        float4 v0, v1;
        v0.x = fmaxf(bf2f(d[0]) * scl + shf, 0.f);
        v0.y = fmaxf(bf2f(d[1]) * scl + shf, 0.f);
        v0.z = fmaxf(bf2f(d[2]) * scl + shf, 0.f);
        v0.w = fmaxf(bf2f(d[3]) * scl + shf, 0.f);
        v1.x = fmaxf(bf2f(d[4]) * scl + shf, 0.f);
        v1.y = fmaxf(bf2f(d[5]) * scl + shf, 0.f);
        v1.z = fmaxf(bf2f(d[6]) * scl + shf, 0.f);
        v1.w = fmaxf(bf2f(d[7]) * scl + shf, 0.f);
        float* op = obase + row * 4096 + g * 8;
        *reinterpret_cast<float4*>(op)     = v0;
        *reinterpret_cast<float4*>(op + 4) = v1;
    }
}

// ---------------------------------------------------------------------------
extern "C" void kernel_launch(void* const* d_in, const int* in_sizes, int n_in,
                              void* d_out, int out_size, void* d_ws, size_t ws_size,
                              hipStream_t stream) {
    const float* x      = (const float*)d_in[0];
    const float* w_off  = (const float*)d_in[1];
    const float* b_off  = (const float*)d_in[2];
    const float* weight = (const float*)d_in[3];
    const float* bias   = (const float*)d_in[4];
    const float* gamma  = (const float*)d_in[5];
    const float* beta   = (const float*)d_in[6];

    char* ws = (char*)d_ws;
    const size_t OFF_XT    = 0;                       // 16,777,216  bf16 xT
    const size_t OFF_WT    = OFF_XT + 16777216;       //  1,179,648  bf16 wTk
    const size_t OFF_WOFT  = OFF_WT + 1179648;        //    147,456  bf16 wofT
    const size_t OFF_Y16   = OFF_WOFT + 147456;       // 16,777,216  bf16 y [pblk][o][px]
    const size_t OFF_SUM   = OFF_Y16 + 16777216;      //      1,024
    const size_t OFF_SUMSQ = OFF_SUM + 1024;          //      1,024

    unsigned short* xT   = (unsigned short*)(ws + OFF_XT);
    unsigned short* wTk  = (unsigned short*)(ws + OFF_WT);
    unsigned short* wofT = (unsigned short*)(ws + OFF_WOFT);
    unsigned short* y16  = (unsigned short*)(ws + OFF_Y16);
    float* gsum  = (float*)(ws + OFF_SUM);
    float* gssq  = (float*)(ws + OFF_SUMSQ);

    k_pack  <<<4640, 256, 0, stream>>>(x, weight, w_off, xT, wTk, wofT, gsum, gssq);
    k_main  <<< 512, 512, 0, stream>>>(xT, wTk, wofT, b_off, bias, y16, gsum, gssq);
    k_bnrelu<<<2048, 256, 0, stream>>>(y16, gsum, gssq, gamma, beta, (float*)d_out);
}